// Round 12
// baseline (2523.256 us; speedup 1.0000x reference)
//
#include <hip/hip_runtime.h>
#include <stdint.h>
#include <stddef.h>

#define S_LEN 2048
#define BATCH 32
#define NIN   256
#define NH    256
#define NG    768   // 3*NH
#define GRUB  32    // gru role blocks
#define XPB   2048  // xproj role blocks (32 rows = 1 step each)

typedef _Float16 half2_t __attribute__((ext_vector_type(2)));
typedef int      int8v   __attribute__((ext_vector_type(8)));
typedef int      int4v   __attribute__((ext_vector_type(4)));

#if __has_builtin(__builtin_amdgcn_exp2f)
#define EXP2F(x) __builtin_amdgcn_exp2f(x)
#else
#define EXP2F(x) exp2f(x)
#endif

static __device__ __forceinline__ float fdot2(half2_t a, half2_t b, float c) {
  return __builtin_amdgcn_fdot2(a, b, c, false);
}
static __device__ __forceinline__ half2_t pack2(float lo, float hi) {
  half2_t r; r[0] = (_Float16)lo; r[1] = (_Float16)hi; return r;
}
static __device__ __forceinline__ float sigmoid_fast(float x) {
  float e = EXP2F(-1.44269504088896340736f * x);
  return 1.0f / (1.0f + e);
}
static __device__ __forceinline__ float tanh_fast(float x) {
  float e = EXP2F(2.88539008177792681472f * x);
  return 1.0f - 2.0f / (1.0f + e);
}
static __device__ __forceinline__ float dpp_xor1(float v) {
  return __builtin_bit_cast(float,
    __builtin_amdgcn_mov_dpp(__builtin_bit_cast(int, v), 0xB1, 0xF, 0xF, true));
}
static __device__ __forceinline__ float dpp_xor2(float v) {
  return __builtin_bit_cast(float,
    __builtin_amdgcn_mov_dpp(__builtin_bit_cast(int, v), 0x4E, 0xF, 0xF, true));
}

// 36 ready-flags in one shot, device-coherent (sc0 sc1 bypasses L1+XCD-L2),
// single base + literal offsets, ONE vmcnt(0) drain per poll.
static __device__ __forceinline__ int flags_all36(const int* p) {
  int4v a0, a1, a2, a3, a4, a5, a6, a7, a8;
  asm volatile("global_load_dwordx4 %0, %9, off sc0 sc1\n"
               "global_load_dwordx4 %1, %9, off offset:16 sc0 sc1\n"
               "global_load_dwordx4 %2, %9, off offset:32 sc0 sc1\n"
               "global_load_dwordx4 %3, %9, off offset:48 sc0 sc1\n"
               "global_load_dwordx4 %4, %9, off offset:64 sc0 sc1\n"
               "global_load_dwordx4 %5, %9, off offset:80 sc0 sc1\n"
               "global_load_dwordx4 %6, %9, off offset:96 sc0 sc1\n"
               "global_load_dwordx4 %7, %9, off offset:112 sc0 sc1\n"
               "global_load_dwordx4 %8, %9, off offset:128 sc0 sc1\n"
               "s_waitcnt vmcnt(0)"
               : "=v"(a0), "=v"(a1), "=v"(a2), "=v"(a3), "=v"(a4),
                 "=v"(a5), "=v"(a6), "=v"(a7), "=v"(a8)
               : "v"(p)
               : "memory");
  int all = a0.x & a0.y & a0.z & a0.w;
  all &= a1.x & a1.y & a1.z & a1.w;
  all &= a2.x & a2.y & a2.z & a2.w;
  all &= a3.x & a3.y & a3.z & a3.w;
  all &= a4.x & a4.y & a4.z & a4.w;
  all &= a5.x & a5.y & a5.z & a5.w;
  all &= a6.x & a6.y & a6.z & a6.w;
  all &= a7.x & a7.y & a7.z & a7.w;
  all &= a8.x & a8.y & a8.z & a8.w;
  return all;
}
#define FLAGWAIT36(BASEP) do {                                                \
    while (!flags_all36(BASEP)) __builtin_amdgcn_s_sleep(16);                 \
  } while (0)

// bit-cast helpers: element extracts use LITERAL indices -> pure SSA
#define BH(x)    __builtin_bit_cast(half2_t, (x))
#define BW(W, e) __builtin_bit_cast(half2_t, (int)((W)[e]))
#define P2I(a, b) __builtin_bit_cast(int, pack2((a), (b)))

// hybrid chunk: one 16B operand (4 half2) against 4 REGISTER row-slices
// (U0..U3 int8v halves, offset o) and 2 LDS-STAGED row-slices (L4,L5 int4v).
// Per-dword order a0..a5 identical to the historical DOT6 -> bit-identical.
#define DOT6H(q, U0, U1, U2, U3, o, L4, L5) do {                              \
    a0 = fdot2(BW(U0,(o)+0), BH(q.x), a0); a1 = fdot2(BW(U1,(o)+0), BH(q.x), a1);\
    a2 = fdot2(BW(U2,(o)+0), BH(q.x), a2); a3 = fdot2(BW(U3,(o)+0), BH(q.x), a3);\
    a4 = fdot2(BW(L4,0), BH(q.x), a4);     a5 = fdot2(BW(L5,0), BH(q.x), a5); \
    a0 = fdot2(BW(U0,(o)+1), BH(q.y), a0); a1 = fdot2(BW(U1,(o)+1), BH(q.y), a1);\
    a2 = fdot2(BW(U2,(o)+1), BH(q.y), a2); a3 = fdot2(BW(U3,(o)+1), BH(q.y), a3);\
    a4 = fdot2(BW(L4,1), BH(q.y), a4);     a5 = fdot2(BW(L5,1), BH(q.y), a5); \
    a0 = fdot2(BW(U0,(o)+2), BH(q.z), a0); a1 = fdot2(BW(U1,(o)+2), BH(q.z), a1);\
    a2 = fdot2(BW(U2,(o)+2), BH(q.z), a2); a3 = fdot2(BW(U3,(o)+2), BH(q.z), a3);\
    a4 = fdot2(BW(L4,2), BH(q.z), a4);     a5 = fdot2(BW(L5,2), BH(q.z), a5); \
    a0 = fdot2(BW(U0,(o)+3), BH(q.w), a0); a1 = fdot2(BW(U1,(o)+3), BH(q.w), a1);\
    a2 = fdot2(BW(U2,(o)+3), BH(q.w), a2); a3 = fdot2(BW(U3,(o)+3), BH(q.w), a3);\
    a4 = fdot2(BW(L4,3), BH(q.w), a4);     a5 = fdot2(BW(L5,3), BH(q.w), a5); \
  } while (0)

#define LDW8(W, o) do {                                                       \
    int4 t0 = wsrc[(o)], t1 = wsrc[(o) + 1];                                  \
    W = (int8v){t0.x, t0.y, t0.z, t0.w, t1.x, t1.y, t1.z, t1.w};              \
  } while (0)

// In-register weights: slices d0..d3 only (128 dwords, 16 int8v). d4,d5 live
// in LDS (see STAGE_WLDS). One 16-operand pin (R4's proven single-asm shape).
#define LOADPIN_W128(SRC)                                                     \
  int8v W00, W01, W02, W03, W10, W11, W12, W13,                               \
        W20, W21, W22, W23, W30, W31, W32, W33;                               \
  {                                                                           \
    const int4* wsrc = (const int4*)(SRC);                                    \
    LDW8(W00, 0);  LDW8(W01, 2);  LDW8(W02, 4);  LDW8(W03, 6);                \
    LDW8(W10, 8);  LDW8(W11, 10); LDW8(W12, 12); LDW8(W13, 14);               \
    LDW8(W20, 16); LDW8(W21, 18); LDW8(W22, 20); LDW8(W23, 22);               \
    LDW8(W30, 24); LDW8(W31, 26); LDW8(W32, 28); LDW8(W33, 30);               \
  }                                                                           \
  asm volatile("" : "+v"(W00), "+v"(W01), "+v"(W02), "+v"(W03),               \
                    "+v"(W10), "+v"(W11), "+v"(W12), "+v"(W13),               \
                    "+v"(W20), "+v"(W21), "+v"(W22), "+v"(W23),               \
                    "+v"(W30), "+v"(W31), "+v"(W32), "+v"(W33));

// Stage slices d4,d5 (64 dwords = global int4 idx 32..47) into LDS at
// [slot s][tid]*16B. Each thread READS ONLY ITS OWN region -> no barrier
// needed; wave reads are 64 contiguous 16B lanes -> conflict-free b128.
#define STAGE_WLDS(SRC)                                                       \
  {                                                                           \
    const int4v* ws4 = (const int4v*)(SRC);                                   \
    int4v* wl = ((int4v*)wsmem) + tid;                                        \
    _Pragma("unroll")                                                         \
    for (int s = 0; s < 16; ++s) wl[s * 512] = ws4[32 + s];                   \
  }

// parity-early quad reduction (bit-identical to quad_sum tree)
#define QREDUCE(MVR, MVZ, MVN) do {                                           \
    float b0 = a0 + dpp_xor1(a0), b1 = a1 + dpp_xor1(a1);                     \
    float b2 = a2 + dpp_xor1(a2), b3 = a3 + dpp_xor1(a3);                     \
    float b4 = a4 + dpp_xor1(a4), b5 = a5 + dpp_xor1(a5);                     \
    float xr_ = jj ? b1 : b0, xz_ = jj ? b3 : b2, xn_ = jj ? b5 : b4;         \
    MVR = xr_ + dpp_xor2(xr_);                                                \
    MVZ = xz_ + dpp_xor2(xz_);                                                \
    MVN = xn_ + dpp_xor2(xn_);                                                \
  } while (0)

// ---------------- prep: weights + flag init (unchanged layout) --------------
__global__ __launch_bounds__(256) void prep_w_kernel(const float* __restrict__ W_ih,
                                                     const float* __restrict__ W_hh,
                                                     const float* __restrict__ b_ih,
                                                     const float* __restrict__ b_hh,
                                                     half2_t* __restrict__ whh3,
                                                     half2_t* __restrict__ wih3,
                                                     float* __restrict__ bias,
                                                     int* __restrict__ flags) {
  int idx = blockIdx.x * 256 + threadIdx.x;
  if (idx < 128 * NG) {
    int tid = idx / 192;
    int r   = idx - tid * 192;
    int d   = r >> 5, kk = r & 31;
    int gate = d >> 1, jj = d & 1;
    int c  = tid & 3, j1 = tid >> 2;
    int row = gate * NH + 2 * j1 + jj;
    int col = 64 * c + 2 * kk;
    whh3[idx] = pack2(W_hh[(size_t)row * NH + col], W_hh[(size_t)row * NH + col + 1]);
  } else if (idx < 2 * 128 * NG) {
    int i2  = idx - 128 * NG;
    int tid = i2 / 192;
    int r   = i2 - tid * 192;
    int d   = r >> 5, kk = r & 31;
    int gate = d >> 1, jj = d & 1;
    int c  = tid & 3, j1 = tid >> 2;
    int row = gate * NH + 2 * j1 + jj;
    int col = 64 * c + 2 * kk;
    wih3[i2] = pack2(W_ih[(size_t)row * NIN + col], W_ih[(size_t)row * NIN + col + 1]);
  } else if (idx < 2 * 128 * NG + NG) {
    int g = idx - 2 * 128 * NG;
    bias[g] = b_ih[g] + b_hh[g];
  } else if (idx < 2 * 128 * NG + NG + XPB + 16) {
    int k = idx - (2 * 128 * NG + NG);
    flags[k] = (k < XPB) ? 0 : 1;   // 16 sentinels for the 36-wide check
  }
}

// ---------------- fused: gru (blocks 0..31) + xproj (blocks 32..2079) -------
// R12: register-demand fix. Pool = 512 regs/SIMD TOTAL (m69) -> 256/wave at
// 2 waves/SIMD; 192-dword weight demand + ~60 working set left no slack, so
// the allocator split 124 arch + 132 acc regardless of granularity
// (R4/R7/R11 all null). This version keeps slices d0..d3 (128 dw) in VGPRs
// and reads d4,d5 (64 dw) from a per-thread LDS region each step (16 b128,
// conflict-free, LDS pipe overlaps VALU). Peak demand ~200 < 256. Decisive
// A/B between "AGPR shuttle" (big win expected) and "4-cyc fdot2" (flat).
__global__
__attribute__((amdgpu_flat_work_group_size(512, 512), amdgpu_waves_per_eu(2, 2)))
void fused_kernel(const float* __restrict__ inf,
                  const half2_t* __restrict__ wih3,
                  const float* __restrict__ bias,
                  float* __restrict__ xp,
                  const half2_t* __restrict__ whh3,
                  float* __restrict__ out,
                  int* __restrict__ flags) {
  const int tid = threadIdx.x;
  const int c   = tid & 3;        // K-quarter
  const int j1  = tid >> 2;       // j-pair index 0..127
  const int jj  = c & 1;          // owned j parity
  const int jmine = 2 * j1 + jj;

  __shared__ __attribute__((aligned(16))) char wsmem[131072];  // [16 slots][512 tid][16B]
  const int4v* wlt = ((const int4v*)wsmem) + tid;

  if (blockIdx.x >= GRUB) {
    // ---------------- xproj role: one time-step (32 rows) ----------------
    const int xb = (int)blockIdx.x - GRUB;
    LOADPIN_W128(wih3 + (size_t)tid * 192);
    STAGE_WLDS(wih3 + (size_t)tid * 192);
    const float bgr = bias[jmine], bgz = bias[NH + jmine], bgn = bias[2 * NH + jmine];
    const float4* fr = (const float4*)(inf + (size_t)xb * 32 * NIN + c * 64);
    float* xo = xp + (size_t)xb * 32 * NG + jmine;
    for (int rr = 0; rr < 32; ++rr) {
      float a0 = 0.f, a1 = 0.f, a2 = 0.f, a3 = 0.f, a4 = 0.f, a5 = 0.f;
      float4 g0, g1; int4 q; int4v l4, l5;
#define XC(IDX, U0, U1, U2, U3, OFF)                                          \
      g0 = fr[2 * (IDX)]; g1 = fr[2 * (IDX) + 1];                             \
      l4 = wlt[(IDX) * 512]; l5 = wlt[((IDX) + 8) * 512];                     \
      q.x = P2I(g0.x, g0.y); q.y = P2I(g0.z, g0.w);                           \
      q.z = P2I(g1.x, g1.y); q.w = P2I(g1.z, g1.w);                           \
      DOT6H(q, U0, U1, U2, U3, OFF, l4, l5);
      XC(0, W00, W10, W20, W30, 0)
      XC(1, W00, W10, W20, W30, 4)
      XC(2, W01, W11, W21, W31, 0)
      XC(3, W01, W11, W21, W31, 4)
      XC(4, W02, W12, W22, W32, 0)
      XC(5, W02, W12, W22, W32, 4)
      XC(6, W03, W13, W23, W33, 0)
      XC(7, W03, W13, W23, W33, 4)
#undef XC
      float mvr, mvz, mvn;
      QREDUCE(mvr, mvz, mvn);
      if (c < 2) {
        float vr = mvr + bgr, vz = mvz + bgz, vn = mvn + bgn;
        // write-through to MALL: no dirty XCD-L2 lines, no wbl2 ever
        asm volatile("global_store_dword %0, %1, off sc0 sc1\n"
                     "global_store_dword %0, %2, off offset:1024 sc0 sc1\n"
                     "global_store_dword %0, %3, off offset:2048 sc0 sc1"
                     :: "v"(xo), "v"(vr), "v"(vz), "v"(vn) : "memory");
      }
      fr += 64;   // next row (256 floats)
      xo += NG;
    }
    __syncthreads();   // per-wave vmcnt(0): all sc0sc1 xp stores MALL-acked
    if (tid == 0) {    // plain device-visible flag store; NO wbl2
      int one = 1;
      asm volatile("global_store_dword %0, %1, off sc0 sc1"
                   :: "v"(&flags[xb]), "v"(one) : "memory");
    }
    return;
  }

  // ---------------- gru role: one batch chain ----------------
  const int b = blockIdx.x;
  LOADPIN_W128(whh3 + (size_t)tid * 192);
  STAGE_WLDS(whh3 + (size_t)tid * 192);

  // 2 buffers x 4 chunks x 144 B (chunk = 64 f16 + 16 B pad) = 1152 B
  __shared__ __attribute__((aligned(16))) char smh[1152];
  if (tid < 288) ((int*)smh)[tid] = 0;

  FLAGWAIT36(flags);   // rows 0..35 ready: covers preload + window-0 prefetches

  const float* xq = xp + (size_t)b * NG + jmine;
  float xr_c = xq[0], xz_c = xq[NH], xn_c = xq[2 * NH];
  xq += (size_t)BATCH * NG;
  float* op = out + (size_t)b * NH + jmine;

  const int wofs = 144 * (jmine >> 6) + 2 * (jmine & 63);

  float h = 0.f;
  __syncthreads();

#define GSTEP(RB, WB) do {                                                    \
    float xr_n = xq[0], xz_n = xq[NH], xn_n = xq[2 * NH];                     \
    const int4* hb4 = (const int4*)(smh + (RB) + c * 144);                    \
    float a0 = 0.f, a1 = 0.f, a2 = 0.f, a3 = 0.f, a4 = 0.f, a5 = 0.f;        \
    int4 qa0 = hb4[0], qa1 = hb4[1], qb0 = hb4[2], qb1 = hb4[3];              \
    int4v lA = wlt[0 * 512], lB = wlt[8 * 512];                               \
    int4v lC = wlt[1 * 512], lD = wlt[9 * 512];                               \
    DOT6H(qa0, W00, W10, W20, W30, 0, lA, lB);                                \
    lA = wlt[2 * 512]; lB = wlt[10 * 512];                                    \
    DOT6H(qa1, W00, W10, W20, W30, 4, lC, lD);                                \
    qa0 = hb4[4]; qa1 = hb4[5];                                               \
    lC = wlt[3 * 512]; lD = wlt[11 * 512];                                    \
    DOT6H(qb0, W01, W11, W21, W31, 0, lA, lB);                                \
    lA = wlt[4 * 512]; lB = wlt[12 * 512];                                    \
    DOT6H(qb1, W01, W11, W21, W31, 4, lC, lD);                                \
    qb0 = hb4[6]; qb1 = hb4[7];                                               \
    lC = wlt[5 * 512]; lD = wlt[13 * 512];                                    \
    DOT6H(qa0, W02, W12, W22, W32, 0, lA, lB);                                \
    lA = wlt[6 * 512]; lB = wlt[14 * 512];                                    \
    DOT6H(qa1, W02, W12, W22, W32, 4, lC, lD);                                \
    lC = wlt[7 * 512]; lD = wlt[15 * 512];                                    \
    DOT6H(qb0, W03, W13, W23, W33, 0, lA, lB);                                \
    DOT6H(qb1, W03, W13, W23, W33, 4, lC, lD);                                \
    float mvr, mvz, mvn;                                                      \
    QREDUCE(mvr, mvz, mvn);                                                   \
    float r = sigmoid_fast(xr_c + mvr);                                       \
    float z = sigmoid_fast(xz_c + mvz);                                       \
    float n = tanh_fast(xn_c + mvn + r * mvn);  /* torch quirk */            \
    h = z * (h - n) + n;                                                      \
    if (c < 2) {                                                              \
      op[0] = h;                                                              \
      *(_Float16*)(smh + (WB) + wofs) = (_Float16)h;                          \
    }                                                                         \
    asm volatile("s_waitcnt lgkmcnt(0)\n\ts_barrier" ::: "memory");           \
    xr_c = xr_n; xz_c = xz_n; xn_c = xn_n;                                    \
    xq += (size_t)BATCH * NG;                                                 \
    op += (size_t)BATCH * NH;                                                 \
  } while (0)

  for (int t0 = 0; t0 < S_LEN; t0 += 8) {
    if (t0 && (t0 & 31) == 0) FLAGWAIT36(flags + t0);  // rows t0..t0+35
    for (int u = 0; u < 4; ++u) {
      GSTEP(0, 576);
      GSTEP(576, 0);
    }
  }
#undef GSTEP

  if (c < 2) out[(size_t)S_LEN * BATCH * NH + (size_t)b * NH + jmine] = h;
}

extern "C" void kernel_launch(void* const* d_in, const int* in_sizes, int n_in,
                              void* d_out, int out_size, void* d_ws, size_t ws_size,
                              hipStream_t stream) {
  const float* input = (const float*)d_in[0];
  const float* W_ih  = (const float*)d_in[1];
  const float* W_hh  = (const float*)d_in[2];
  const float* b_ih  = (const float*)d_in[3];
  const float* b_hh  = (const float*)d_in[4];
  float* out = (float*)d_out;

  const size_t SB = (size_t)S_LEN * BATCH;           // 65536
  const size_t xp_b = SB * NG * 4;                   // 192 MiB
  const size_t w_b  = (size_t)128 * NG * 4;          // 384 KiB each

  char* p = (char*)d_ws;
  float*    xp    = (float*)p;                p += xp_b;
  half2_t*  whh3  = (half2_t*)p;              p += w_b;
  half2_t*  wih3  = (half2_t*)p;              p += w_b;
  float*    bias  = (float*)p;                p += (size_t)NG * 4;
  uintptr_t fp_ = (((uintptr_t)p) + 127) & ~(uintptr_t)127;
  int*      flags = (int*)fp_;                // 2064 ints (2048 + 16 sentinels)

  const int prep_items = 2 * 128 * NG + NG + XPB + 16;
  prep_w_kernel<<<(prep_items + 255) / 256, 256, 0, stream>>>(W_ih, W_hh, b_ih, b_hh,
                                                              whh3, wih3, bias, flags);
  fused_kernel<<<GRUB + XPB, 512, 0, stream>>>(input, wih3, bias, xp, whh3, out, flags);
  (void)out_size; (void)n_in; (void)in_sizes; (void)ws_size;
}

// Round 13
// 2325.266 us; speedup vs baseline: 1.0851x; 1.0851x over previous
//
#include <hip/hip_runtime.h>
#include <stdint.h>
#include <stddef.h>

#define S_LEN 2048
#define BATCH 32
#define NIN   256
#define NH    256
#define NG    768   // 3*NH
#define GRUB  32    // gru role blocks
#define XPB   2048  // xproj role blocks (32 rows = 1 step each)

typedef _Float16 half2_t __attribute__((ext_vector_type(2)));
typedef int      int16v  __attribute__((ext_vector_type(16)));
typedef int      int4v   __attribute__((ext_vector_type(4)));

#if __has_builtin(__builtin_amdgcn_exp2f)
#define EXP2F(x) __builtin_amdgcn_exp2f(x)
#else
#define EXP2F(x) exp2f(x)
#endif

static __device__ __forceinline__ float fdot2(half2_t a, half2_t b, float c) {
  return __builtin_amdgcn_fdot2(a, b, c, false);
}
static __device__ __forceinline__ half2_t pack2(float lo, float hi) {
  half2_t r; r[0] = (_Float16)lo; r[1] = (_Float16)hi; return r;
}
static __device__ __forceinline__ float sigmoid_fast(float x) {
  float e = EXP2F(-1.44269504088896340736f * x);
  return 1.0f / (1.0f + e);
}
static __device__ __forceinline__ float tanh_fast(float x) {
  float e = EXP2F(2.88539008177792681472f * x);
  return 1.0f - 2.0f / (1.0f + e);
}
static __device__ __forceinline__ float dpp_xor1(float v) {
  return __builtin_bit_cast(float,
    __builtin_amdgcn_mov_dpp(__builtin_bit_cast(int, v), 0xB1, 0xF, 0xF, true));
}
static __device__ __forceinline__ float dpp_xor2(float v) {
  return __builtin_bit_cast(float,
    __builtin_amdgcn_mov_dpp(__builtin_bit_cast(int, v), 0x4E, 0xF, 0xF, true));
}

// 36 ready-flags in one shot, device-coherent (sc0 sc1 bypasses L1+XCD-L2),
// single base + literal offsets, ONE vmcnt(0) drain per poll.
static __device__ __forceinline__ int flags_all36(const int* p) {
  int4v a0, a1, a2, a3, a4, a5, a6, a7, a8;
  asm volatile("global_load_dwordx4 %0, %9, off sc0 sc1\n"
               "global_load_dwordx4 %1, %9, off offset:16 sc0 sc1\n"
               "global_load_dwordx4 %2, %9, off offset:32 sc0 sc1\n"
               "global_load_dwordx4 %3, %9, off offset:48 sc0 sc1\n"
               "global_load_dwordx4 %4, %9, off offset:64 sc0 sc1\n"
               "global_load_dwordx4 %5, %9, off offset:80 sc0 sc1\n"
               "global_load_dwordx4 %6, %9, off offset:96 sc0 sc1\n"
               "global_load_dwordx4 %7, %9, off offset:112 sc0 sc1\n"
               "global_load_dwordx4 %8, %9, off offset:128 sc0 sc1\n"
               "s_waitcnt vmcnt(0)"
               : "=v"(a0), "=v"(a1), "=v"(a2), "=v"(a3), "=v"(a4),
                 "=v"(a5), "=v"(a6), "=v"(a7), "=v"(a8)
               : "v"(p)
               : "memory");
  int all = a0.x & a0.y & a0.z & a0.w;
  all &= a1.x & a1.y & a1.z & a1.w;
  all &= a2.x & a2.y & a2.z & a2.w;
  all &= a3.x & a3.y & a3.z & a3.w;
  all &= a4.x & a4.y & a4.z & a4.w;
  all &= a5.x & a5.y & a5.z & a5.w;
  all &= a6.x & a6.y & a6.z & a6.w;
  all &= a7.x & a7.y & a7.z & a7.w;
  all &= a8.x & a8.y & a8.z & a8.w;
  return all;
}
#define FLAGWAIT36(BASEP) do {                                                \
    while (!flags_all36(BASEP)) __builtin_amdgcn_s_sleep(16);                 \
  } while (0)

// bit-cast helpers: element extracts use LITERAL indices -> pure SSA
#define BH(x)    __builtin_bit_cast(half2_t, (x))
#define BW(W, e) __builtin_bit_cast(half2_t, (int)((W)[e]))
#define P2I(a, b) __builtin_bit_cast(int, pack2((a), (b)))

// one 16B operand chunk (4 half2) against 6 row-slices (2j x 3 gates).
// Weight as src0. Accumulator reuse distance 6 -> no VALU dep stalls.
#define DOT6(q, U0, U1, U2, U3, U4, U5, o) do {                               \
    a0 = fdot2(BW(U0,(o)+0), BH(q.x), a0); a1 = fdot2(BW(U1,(o)+0), BH(q.x), a1);\
    a2 = fdot2(BW(U2,(o)+0), BH(q.x), a2); a3 = fdot2(BW(U3,(o)+0), BH(q.x), a3);\
    a4 = fdot2(BW(U4,(o)+0), BH(q.x), a4); a5 = fdot2(BW(U5,(o)+0), BH(q.x), a5);\
    a0 = fdot2(BW(U0,(o)+1), BH(q.y), a0); a1 = fdot2(BW(U1,(o)+1), BH(q.y), a1);\
    a2 = fdot2(BW(U2,(o)+1), BH(q.y), a2); a3 = fdot2(BW(U3,(o)+1), BH(q.y), a3);\
    a4 = fdot2(BW(U4,(o)+1), BH(q.y), a4); a5 = fdot2(BW(U5,(o)+1), BH(q.y), a5);\
    a0 = fdot2(BW(U0,(o)+2), BH(q.z), a0); a1 = fdot2(BW(U1,(o)+2), BH(q.z), a1);\
    a2 = fdot2(BW(U2,(o)+2), BH(q.z), a2); a3 = fdot2(BW(U3,(o)+2), BH(q.z), a3);\
    a4 = fdot2(BW(U4,(o)+2), BH(q.z), a4); a5 = fdot2(BW(U5,(o)+2), BH(q.z), a5);\
    a0 = fdot2(BW(U0,(o)+3), BH(q.w), a0); a1 = fdot2(BW(U1,(o)+3), BH(q.w), a1);\
    a2 = fdot2(BW(U2,(o)+3), BH(q.w), a2); a3 = fdot2(BW(U3,(o)+3), BH(q.w), a3);\
    a4 = fdot2(BW(U4,(o)+3), BH(q.w), a4); a5 = fdot2(BW(U5,(o)+3), BH(q.w), a5);\
  } while (0)

#define LDW(W, o) do {                                                        \
    int4 q0 = wsrc[(o) + 0], q1 = wsrc[(o) + 1];                              \
    int4 q2 = wsrc[(o) + 2], q3 = wsrc[(o) + 3];                              \
    W = (int16v){q0.x, q0.y, q0.z, q0.w, q1.x, q1.y, q1.z, q1.w,              \
                 q2.x, q2.y, q2.z, q2.w, q3.x, q3.y, q3.z, q3.w};             \
  } while (0)

// load 48 int4 of weights into 12 pinned int16v (R4/R7 pattern: compiles and
// passes; values asm-opaque so loads cannot sink into the loop). Weights end
// up AGPR-resident (VGPR_Count ~124) -- benign on gfx950's unified file:
// fdot2 sources AGPRs directly (R12 falsified the shuttle theory).
#define LOADPIN_W(SRC) \
  int16v W0a, W0b, W1a, W1b, W2a, W2b, W3a, W3b, W4a, W4b, W5a, W5b;         \
  {                                                                           \
    const int4* wsrc = (const int4*)(SRC);                                    \
    LDW(W0a, 0);  LDW(W0b, 4);  LDW(W1a, 8);  LDW(W1b, 12);                   \
    LDW(W2a, 16); LDW(W2b, 20); LDW(W3a, 24); LDW(W3b, 28);                   \
    LDW(W4a, 32); LDW(W4b, 36); LDW(W5a, 40); LDW(W5b, 44);                   \
  }                                                                           \
  asm volatile("" : "+v"(W0a), "+v"(W0b), "+v"(W1a), "+v"(W1b),               \
                    "+v"(W2a), "+v"(W2b), "+v"(W3a), "+v"(W3b),               \
                    "+v"(W4a), "+v"(W4b), "+v"(W5a), "+v"(W5b));

// 8 chunks of 16B against the full 6-row slice set (gru path)
#define DOT6x8() do {                                                         \
    DOT6(q0, W0a, W1a, W2a, W3a, W4a, W5a, 0);                                \
    DOT6(q1, W0a, W1a, W2a, W3a, W4a, W5a, 4);                                \
    DOT6(q2, W0a, W1a, W2a, W3a, W4a, W5a, 8);                                \
    DOT6(q3, W0a, W1a, W2a, W3a, W4a, W5a, 12);                               \
    DOT6(q4, W0b, W1b, W2b, W3b, W4b, W5b, 0);                                \
    DOT6(q5, W0b, W1b, W2b, W3b, W4b, W5b, 4);                                \
    DOT6(q6, W0b, W1b, W2b, W3b, W4b, W5b, 8);                                \
    DOT6(q7, W0b, W1b, W2b, W3b, W4b, W5b, 12);                               \
  } while (0)

// parity-early quad reduction (bit-identical to quad_sum tree, 6 fewer VALU)
#define QREDUCE(MVR, MVZ, MVN) do {                                           \
    float b0 = a0 + dpp_xor1(a0), b1 = a1 + dpp_xor1(a1);                     \
    float b2 = a2 + dpp_xor1(a2), b3 = a3 + dpp_xor1(a3);                     \
    float b4 = a4 + dpp_xor1(a4), b5 = a5 + dpp_xor1(a5);                     \
    float xr_ = jj ? b1 : b0, xz_ = jj ? b3 : b2, xn_ = jj ? b5 : b4;         \
    MVR = xr_ + dpp_xor2(xr_);                                                \
    MVZ = xz_ + dpp_xor2(xz_);                                                \
    MVN = xn_ + dpp_xor2(xn_);                                                \
  } while (0)

// ---------------- prep: weights + flag init ----------------
// whh3/wih3 layout (G=6/S=4): thread tid = j1*4+c owns 192 contiguous dwords
// [d][kk], d = gate*2+jj in 0..5, kk in 0..31: half2 of
// W[row = gate*256 + 2*j1 + jj][col = 64*c + 2*kk .. +1].
__global__ __launch_bounds__(256) void prep_w_kernel(const float* __restrict__ W_ih,
                                                     const float* __restrict__ W_hh,
                                                     const float* __restrict__ b_ih,
                                                     const float* __restrict__ b_hh,
                                                     half2_t* __restrict__ whh3,
                                                     half2_t* __restrict__ wih3,
                                                     float* __restrict__ bias,
                                                     int* __restrict__ flags) {
  int idx = blockIdx.x * 256 + threadIdx.x;
  if (idx < 128 * NG) {
    int tid = idx / 192;
    int r   = idx - tid * 192;
    int d   = r >> 5, kk = r & 31;
    int gate = d >> 1, jj = d & 1;
    int c  = tid & 3, j1 = tid >> 2;
    int row = gate * NH + 2 * j1 + jj;
    int col = 64 * c + 2 * kk;
    whh3[idx] = pack2(W_hh[(size_t)row * NH + col], W_hh[(size_t)row * NH + col + 1]);
  } else if (idx < 2 * 128 * NG) {
    int i2  = idx - 128 * NG;
    int tid = i2 / 192;
    int r   = i2 - tid * 192;
    int d   = r >> 5, kk = r & 31;
    int gate = d >> 1, jj = d & 1;
    int c  = tid & 3, j1 = tid >> 2;
    int row = gate * NH + 2 * j1 + jj;
    int col = 64 * c + 2 * kk;
    wih3[i2] = pack2(W_ih[(size_t)row * NIN + col], W_ih[(size_t)row * NIN + col + 1]);
  } else if (idx < 2 * 128 * NG + NG) {
    int g = idx - 2 * 128 * NG;
    bias[g] = b_ih[g] + b_hh[g];
  } else if (idx < 2 * 128 * NG + NG + XPB + 16) {
    int k = idx - (2 * 128 * NG + NG);
    flags[k] = (k < XPB) ? 0 : 1;   // 16 sentinels for the 36-wide check
  }
}

// ---------------- fused: gru (blocks 0..31) + xproj (blocks 32..2079) -------
// R13 = exact R10 revert (best passing, 2332.7us). R12's LDS-hybrid was an
// invalid experiment (VGPR stayed 116 at demand ~200 -> allocator AGPR split
// is not demand-driven) and regressed 200us from added LDS issue. Final
// model: no shuttles exist (unified file, fdot2 sources AGPRs); measured
// ~2240 cyc/SIMD/step VALU busy IS the mandatory 384 dot2 wave-insts at
// ~5.3 cyc effective. Chain is VALU-issue-bound at 84-95% of wall; xproj
// fully hidden; sc0sc1 write-through avoids wbl2 L2 flushes.
__global__
__attribute__((amdgpu_flat_work_group_size(512, 512), amdgpu_waves_per_eu(2, 2)))
void fused_kernel(const float* __restrict__ inf,
                  const half2_t* __restrict__ wih3,
                  const float* __restrict__ bias,
                  float* __restrict__ xp,
                  const half2_t* __restrict__ whh3,
                  float* __restrict__ out,
                  int* __restrict__ flags) {
  const int tid = threadIdx.x;
  const int c   = tid & 3;        // K-quarter
  const int j1  = tid >> 2;       // j-pair index 0..127
  const int jj  = c & 1;          // owned j parity
  const int jmine = 2 * j1 + jj;

  if (blockIdx.x >= GRUB) {
    // ---------------- xproj role: one time-step (32 rows) ----------------
    const int xb = (int)blockIdx.x - GRUB;
    LOADPIN_W(wih3 + (size_t)tid * 192);
    const float bgr = bias[jmine], bgz = bias[NH + jmine], bgn = bias[2 * NH + jmine];
    const float4* fr = (const float4*)(inf + (size_t)xb * 32 * NIN + c * 64);
    float* xo = xp + (size_t)xb * 32 * NG + jmine;
    for (int rr = 0; rr < 32; ++rr) {
      float a0 = 0.f, a1 = 0.f, a2 = 0.f, a3 = 0.f, a4 = 0.f, a5 = 0.f;
      float4 g0, g1; int4 q;
#define XB(IDX, U0, U1, U2, U3, U4, U5, OFF)                                  \
      g0 = fr[2 * (IDX)]; g1 = fr[2 * (IDX) + 1];                             \
      q.x = P2I(g0.x, g0.y); q.y = P2I(g0.z, g0.w);                           \
      q.z = P2I(g1.x, g1.y); q.w = P2I(g1.z, g1.w);                           \
      DOT6(q, U0, U1, U2, U3, U4, U5, OFF);
      XB(0, W0a, W1a, W2a, W3a, W4a, W5a, 0)
      XB(1, W0a, W1a, W2a, W3a, W4a, W5a, 4)
      XB(2, W0a, W1a, W2a, W3a, W4a, W5a, 8)
      XB(3, W0a, W1a, W2a, W3a, W4a, W5a, 12)
      XB(4, W0b, W1b, W2b, W3b, W4b, W5b, 0)
      XB(5, W0b, W1b, W2b, W3b, W4b, W5b, 4)
      XB(6, W0b, W1b, W2b, W3b, W4b, W5b, 8)
      XB(7, W0b, W1b, W2b, W3b, W4b, W5b, 12)
#undef XB
      float mvr, mvz, mvn;
      QREDUCE(mvr, mvz, mvn);
      if (c < 2) {
        float vr = mvr + bgr, vz = mvz + bgz, vn = mvn + bgn;
        // write-through to MALL: no dirty XCD-L2 lines, nothing to wbl2 later
        asm volatile("global_store_dword %0, %1, off sc0 sc1\n"
                     "global_store_dword %0, %2, off offset:1024 sc0 sc1\n"
                     "global_store_dword %0, %3, off offset:2048 sc0 sc1"
                     :: "v"(xo), "v"(vr), "v"(vz), "v"(vn) : "memory");
      }
      fr += 64;   // next row (256 floats)
      xo += NG;
    }
    __syncthreads();   // per-wave vmcnt(0): all sc0sc1 xp stores MALL-acked
    if (tid == 0) {    // plain device-visible flag store; NO wbl2
      int one = 1;
      asm volatile("global_store_dword %0, %1, off sc0 sc1"
                   :: "v"(&flags[xb]), "v"(one) : "memory");
    }
    return;
  }

  // ---------------- gru role: one batch chain ----------------
  const int b = blockIdx.x;
  LOADPIN_W(whh3 + (size_t)tid * 192);

  // 2 buffers x 4 chunks x 144 B (chunk = 64 f16 + 16 B pad) = 1152 B
  __shared__ __attribute__((aligned(16))) char smh[1152];
  if (tid < 288) ((int*)smh)[tid] = 0;

  FLAGWAIT36(flags);   // rows 0..35 ready: covers preload + window-0 prefetches

  const float* xq = xp + (size_t)b * NG + jmine;
  float xr_c = xq[0], xz_c = xq[NH], xn_c = xq[2 * NH];
  xq += (size_t)BATCH * NG;
  float* op = out + (size_t)b * NH + jmine;

  const int wofs = 144 * (jmine >> 6) + 2 * (jmine & 63);

  float h = 0.f;
  __syncthreads();

#define GSTEP(RB, WB) do {                                                    \
    float xr_n = xq[0], xz_n = xq[NH], xn_n = xq[2 * NH];                     \
    const char* hb = smh + (RB) + c * 144;                                    \
    float a0 = 0.f, a1 = 0.f, a2 = 0.f, a3 = 0.f, a4 = 0.f, a5 = 0.f;        \
    int4 q0 = *(const int4*)(hb +   0), q1 = *(const int4*)(hb +  16);       \
    int4 q2 = *(const int4*)(hb +  32), q3 = *(const int4*)(hb +  48);       \
    int4 q4 = *(const int4*)(hb +  64), q5 = *(const int4*)(hb +  80);       \
    int4 q6 = *(const int4*)(hb +  96), q7 = *(const int4*)(hb + 112);       \
    DOT6x8();                                                                 \
    float mvr, mvz, mvn;                                                      \
    QREDUCE(mvr, mvz, mvn);                                                   \
    float r = sigmoid_fast(xr_c + mvr);                                       \
    float z = sigmoid_fast(xz_c + mvz);                                       \
    float n = tanh_fast(xn_c + mvn + r * mvn);  /* torch quirk */            \
    h = z * (h - n) + n;                                                      \
    if (c < 2) {                                                              \
      op[0] = h;                                                              \
      *(_Float16*)(smh + (WB) + wofs) = (_Float16)h;                          \
    }                                                                         \
    asm volatile("s_waitcnt lgkmcnt(0)\n\ts_barrier" ::: "memory");           \
    xr_c = xr_n; xz_c = xz_n; xn_c = xn_n;                                    \
    xq += (size_t)BATCH * NG;                                                 \
    op += (size_t)BATCH * NH;                                                 \
  } while (0)

  for (int t0 = 0; t0 < S_LEN; t0 += 8) {
    if (t0 && (t0 & 31) == 0) FLAGWAIT36(flags + t0);  // rows t0..t0+35
    for (int u = 0; u < 4; ++u) {
      GSTEP(0, 576);
      GSTEP(576, 0);
    }
  }
#undef GSTEP

  if (c < 2) out[(size_t)S_LEN * BATCH * NH + (size_t)b * NH + jmine] = h;
}

extern "C" void kernel_launch(void* const* d_in, const int* in_sizes, int n_in,
                              void* d_out, int out_size, void* d_ws, size_t ws_size,
                              hipStream_t stream) {
  const float* input = (const float*)d_in[0];
  const float* W_ih  = (const float*)d_in[1];
  const float* W_hh  = (const float*)d_in[2];
  const float* b_ih  = (const float*)d_in[3];
  const float* b_hh  = (const float*)d_in[4];
  float* out = (float*)d_out;

  const size_t SB = (size_t)S_LEN * BATCH;           // 65536
  const size_t xp_b = SB * NG * 4;                   // 192 MiB
  const size_t w_b  = (size_t)128 * NG * 4;          // 384 KiB each

  char* p = (char*)d_ws;
  float*    xp    = (float*)p;                p += xp_b;
  half2_t*  whh3  = (half2_t*)p;              p += w_b;
  half2_t*  wih3  = (half2_t*)p;              p += w_b;
  float*    bias  = (float*)p;                p += (size_t)NG * 4;
  uintptr_t fp_ = (((uintptr_t)p) + 127) & ~(uintptr_t)127;
  int*      flags = (int*)fp_;                // 2064 ints (2048 + 16 sentinels)

  const int prep_items = 2 * 128 * NG + NG + XPB + 16;
  prep_w_kernel<<<(prep_items + 255) / 256, 256, 0, stream>>>(W_ih, W_hh, b_ih, b_hh,
                                                              whh3, wih3, bias, flags);
  fused_kernel<<<GRUB + XPB, 512, 0, stream>>>(input, wih3, bias, xp, whh3, out, flags);
  (void)out_size; (void)n_in; (void)in_sizes; (void)ws_size;
}